// Round 9
// baseline (279.499 us; speedup 1.0000x reference)
//
#include <hip/hip_runtime.h>
#include <math.h>

typedef unsigned short u16;
typedef unsigned int u32;

#define N_ROWS 8192
#define DDIM 512
#define HDIM 1024
#define ODIM 512
#define NEXP 8
#define MAXPAIRS (N_ROWS * 2)          // 16384
#define MAXPOS (MAXPAIRS + NEXP * 128) // 17408 (per-expert segments 128-aligned)
#define MAXTILES (MAXPOS / 128)        // 136

// small-region word indices (in d_ws)
#define SM_CNT 0   // 8 ints: expert lengths
#define SM_CUR 8   // 8 ints: scatter cursors
#define SM_AOFF 16 // 9 ints: aligned bucket offsets
#define SM_GSUM 32 // 8 floats: sum of gates per expert
#define SM_LSUM 40 // 8 floats: sum of load_probs per expert
#define SM_WORDS 64

using short8 = __attribute__((ext_vector_type(8))) short;
using float4v = __attribute__((ext_vector_type(4))) float;

__device__ __forceinline__ u16 f2bf(float f) {
    union { float f; u32 u; } v; v.f = f;
    u32 u = v.u;
    return (u16)((u + 0x7fffu + ((u >> 16) & 1u)) >> 16);
}

// async global->LDS, 16B per lane; HW places lane i at lds_base + i*16
__device__ __forceinline__ void async_copy16(u16* lds, const u16* g) {
    __builtin_amdgcn_global_load_lds(
        (const __attribute__((address_space(1))) void*)g,
        (__attribute__((address_space(3))) void*)lds, 16, 0, 0);
}

// ---------------- init1: zero small + zeropage (must precede combo's gating atomics) ----------------
__global__ __launch_bounds__(512) void init1_kernel(int* small, float* zeropage) {
    int i = threadIdx.x;
    if (i < SM_WORDS) small[i] = 0;
    zeropage[i] = 0.f; // 512 floats
}

// ---------------- combo: gating + W1/W2 convert + ow transpose + bucket init ----------------
// R8: prep (HBM-bound, ~35us) and gating (VALU/LDS-bound, ~20us) have no data
// dependency -> one dispatch, block-range branching, so they overlap instead of
// serializing on the stream.
#define CONV_BLOCKS 8192 // 2 * (8*1024*512/4) / 256
#define GATE_BLOCKS 512  // N_ROWS/16
__global__ __launch_bounds__(256) void combo_kernel(
    const float* __restrict__ x, const float* __restrict__ noise,
    const float* __restrict__ norm_w, const float* __restrict__ norm_b,
    const float* __restrict__ w_gate, const float* __restrict__ w_noise,
    const float* __restrict__ W1, const float* __restrict__ W2, const float* __restrict__ ow,
    u16* __restrict__ xnorm_bf, u16* __restrict__ x_bf,
    int* __restrict__ pair_expert, float* __restrict__ pair_gate,
    u16* __restrict__ W1b, u16* __restrict__ W2b, u16* __restrict__ owT,
    int* __restrict__ small, int* __restrict__ bucket_rows)
{
    __shared__ __align__(16) float sh[NEXP * DDIM * 2 + 64];
    int b = blockIdx.x, tid = threadIdx.x;

    if (b >= GATE_BLOCKS) {
        int cb = b - GATE_BLOCKS;
        if (cb < CONV_BLOCKS) {
            const size_t n4 = (size_t)NEXP * HDIM * DDIM / 4;
            size_t i = (size_t)cb * 256 + tid;
            const float* src; u16* dst;
            if (i < n4) { src = W1; dst = W1b; } else { src = W2; dst = W2b; i -= n4; }
            float4 v = ((const float4*)src)[i];
            ushort4 o;
            o.x = f2bf(v.x); o.y = f2bf(v.y); o.z = f2bf(v.z); o.w = f2bf(v.w);
            ((ushort4*)dst)[i] = o;
        } else if (cb < CONV_BLOCKS + 256) {
            float (*tile)[33] = (float(*)[33])sh;
            int t = cb - CONV_BLOCKS;
            int bx = (t & 15) * 32, by = (t >> 4) * 32;
            int tx = tid & 31, ty = tid >> 5; // 32 x 8
            for (int r = ty; r < 32; r += 8) tile[r][tx] = ow[(size_t)(by + r) * ODIM + bx + tx];
            __syncthreads();
            for (int r = ty; r < 32; r += 8) owT[(size_t)(bx + r) * DDIM + by + tx] = f2bf(tile[tx][r]);
        } else {
            int i = (cb - CONV_BLOCKS - 256) * 256 + tid;
            if (i < MAXPOS) bucket_rows[i] = -1;
        }
        return;
    }

    // ---- gating body (block b of 512) ----
    float* wgT = sh;                   // [e][d] transposed -> conflict-free reads
    float* wnT = sh + NEXP * DDIM;
    float* blk_g = sh + 2 * NEXP * DDIM;
    float* blk_l = blk_g + NEXP;
    int* blk_c = (int*)(blk_l + NEXP);
    float* smf = (float*)small;

    for (int i = tid; i < NEXP * DDIM; i += 256) {
        int d = i >> 3, e = i & 7;
        wgT[e * DDIM + d] = w_gate[i];
        wnT[e * DDIM + d] = w_noise[i];
    }
    if (tid < NEXP) { blk_g[tid] = 0.f; blk_l[tid] = 0.f; blk_c[tid] = 0; }
    __syncthreads();

    int wave = tid >> 6, lane = tid & 63;
    float nw[8], nb[8];
#pragma unroll
    for (int j = 0; j < 8; j++) { nw[j] = norm_w[j * 64 + lane]; nb[j] = norm_b[j * 64 + lane]; }

    for (int r = 0; r < 4; ++r) {
        int row = b * 16 + wave * 4 + r;
        const float* xr = x + (size_t)row * DDIM;
        float xv[8], s = 0.f, s2 = 0.f;
#pragma unroll
        for (int j = 0; j < 8; j++) { float v = xr[j * 64 + lane]; xv[j] = v; s += v; s2 += v * v; }
#pragma unroll
        for (int o = 32; o; o >>= 1) { s += __shfl_xor(s, o, 64); s2 += __shfl_xor(s2, o, 64); }
        float mu = s * (1.f / DDIM);
        float var = s2 * (1.f / DDIM) - mu * mu;
        float rstd = rsqrtf(var + 1e-6f);

        float acc[16];
#pragma unroll
        for (int e = 0; e < 16; e++) acc[e] = 0.f;
#pragma unroll
        for (int j = 0; j < 8; j++) {
            float v = (xv[j] - mu) * rstd * nw[j] + nb[j];
            int d = j * 64 + lane;
            xnorm_bf[(size_t)row * DDIM + d] = f2bf(v);
            x_bf[(size_t)row * DDIM + d] = f2bf(xv[j]);
#pragma unroll
            for (int e = 0; e < 8; e++) {
                acc[e] += v * wgT[e * DDIM + d];
                acc[8 + e] += v * wnT[e * DDIM + d];
            }
        }
#pragma unroll
        for (int e = 0; e < 16; e++)
#pragma unroll
            for (int o = 32; o; o >>= 1) acc[e] += __shfl_xor(acc[e], o, 64);

        float cl[8], sd[8], nz[8];
#pragma unroll
        for (int e = 0; e < 8; e++) {
            cl[e] = acc[e];
            float t = acc[8 + e];
            float sp = fmaxf(t, 0.f) + log1pf(expf(-fabsf(t))); // stable softplus
            sd[e] = sp + 0.01f;
            nz[e] = cl[e] + noise[(size_t)row * NEXP + e] * sd[e];
        }
        // top-3 (strict > = lowest-index tie-break, matching lax.top_k)
        int idx[3]; float val[3]; u32 msk = 0;
#pragma unroll
        for (int t = 0; t < 3; t++) {
            float best = -INFINITY; int bi = 0;
#pragma unroll
            for (int e = 0; e < 8; e++)
                if (!((msk >> e) & 1) && nz[e] > best) { best = nz[e]; bi = e; }
            idx[t] = bi; val[t] = best; msk |= 1u << bi;
        }
        float e1 = expf(val[1] - val[0]);
        float g0 = 1.f / (1.f + e1), g1 = e1 / (1.f + e1);
        float thr_in = val[2], thr_out = val[1];

        if (lane == 0) {
            pair_expert[row * 2] = idx[0]; pair_gate[row * 2] = g0;
            pair_expert[row * 2 + 1] = idx[1]; pair_gate[row * 2 + 1] = g1;
            atomicAdd(&blk_g[idx[0]], g0); atomicAdd(&blk_g[idx[1]], g1);
            atomicAdd(&blk_c[idx[0]], 1); atomicAdd(&blk_c[idx[1]], 1);
#pragma unroll
            for (int e = 0; e < 8; e++) {
                float thr = (nz[e] > thr_in) ? thr_in : thr_out;
                float z = (cl[e] - thr) / sd[e];
                float p = 0.5f * (1.f + erff(z * 0.70710678118654752f));
                atomicAdd(&blk_l[e], p);
            }
        }
    }
    __syncthreads();
    if (tid < NEXP) {
        atomicAdd(smf + SM_GSUM + tid, blk_g[tid]);
        atomicAdd(smf + SM_LSUM + tid, blk_l[tid]);
        atomicAdd(&small[SM_CNT + tid], blk_c[tid]);
    }
}

// ---------------- scatter (+prefix +loss +load) ----------------
__global__ __launch_bounds__(256) void scatter_kernel(
    const int* __restrict__ pair_expert, const float* __restrict__ pair_gate,
    int* __restrict__ small, int* __restrict__ bucket_rows, float* __restrict__ gate_by_pos,
    float* __restrict__ out_loss, float* __restrict__ out_load)
{
    __shared__ int aoff[NEXP + 1];
    __shared__ int blk_cnt[NEXP];
    __shared__ int blk_base[NEXP];
    int tid = threadIdx.x;
    if (tid == 0) {
        int acc = 0; aoff[0] = 0;
        for (int e = 0; e < NEXP; e++) { acc += (small[SM_CNT + e] + 127) & ~127; aoff[e + 1] = acc; }
    }
    if (tid < NEXP) blk_cnt[tid] = 0;
    __syncthreads();
    int p = blockIdx.x * 256 + tid;
    int e = pair_expert[p];
    int local = atomicAdd(&blk_cnt[e], 1);
    __syncthreads();
    if (tid < NEXP)
        blk_base[tid] = aoff[tid] + atomicAdd(&small[SM_CUR + tid], blk_cnt[tid]);
    if (blockIdx.x == 0 && tid < NEXP + 1) small[SM_AOFF + tid] = aoff[tid];
    __syncthreads();
    int pos = blk_base[e] + local;
    bucket_rows[pos] = p >> 1;
    gate_by_pos[pos] = pair_gate[p];

    if (blockIdx.x == 0 && tid == 0) {
        const float* gs = (const float*)small + SM_GSUM;
        const float* ls = (const float*)small + SM_LSUM;
        float cv[2];
        for (int t = 0; t < 2; t++) {
            const float* v = t ? ls : gs;
            float m = 0.f;
            for (int k = 0; k < NEXP; k++) m += v[k];
            m *= (1.f / NEXP);
            float var = 0.f;
            for (int k = 0; k < NEXP; k++) { float d = v[k] - m; var += d * d; }
            var *= (1.f / NEXP);
            cv[t] = var / (m * m + 1e-10f);
        }
        out_loss[0] = 0.01f * (cv[0] + cv[1]);
        int tot = 0;
        for (int k = 0; k < NEXP; k++) tot += small[SM_CNT + k];
        float inv = 1.f / (float)tot;
        for (int k = 0; k < NEXP; k++) out_load[k] = (float)small[SM_CNT + k] * inv;
    }
}

// ---------------- R8 GEMM: 128x128 tiles, BK=64, swizzled, single-buffer ----------------
// Cross-round A/B on gemmB: 128x128/BK32=51us (R2/R3), 128x64=63 (R5),
// split-K=76 (R6), dbuf=69 (R7). MFMA-inst-per-staged-KB (4 vs 2.7) is the
// variable that tracks perf -> both gemms use 128x128. Swizzle keeps
// SQ_LDS_BANK_CONFLICT at 0 (R5-verified). LDS 32KB -> 5 blocks/CU cap.

// gemmA: y<8: gathered x_norm @ W1[e]^T, +b1, SiLU -> a_buf bf16 (K=512, N=1024)
//        y>=8: x_bf @ owT^T -> y fp32 (j=(y-8)*136+x over 64x4 tiles)
__global__ __launch_bounds__(256) void gemmA_kernel(
    const u16* __restrict__ xnorm, const u16* __restrict__ xbf,
    const u16* __restrict__ W1b, const u16* __restrict__ owT,
    const int* __restrict__ bucket_rows, const int* __restrict__ small,
    const float* __restrict__ b1, const u16* __restrict__ zeropage,
    u16* __restrict__ a_buf, float* __restrict__ y)
{
    constexpr int KD = 512;
    __shared__ __align__(16) u16 As[128 * 64];
    __shared__ __align__(16) u16 Bs[128 * 64];

    int tid = threadIdx.x;
    bool m0 = blockIdx.y < 8;
    int base, bn, e = 0;
    const u16* Bsel;
    if (m0) {
        base = blockIdx.x * 128;
        if (base >= small[SM_AOFF + 8]) return;
        while (e < 7 && base >= small[SM_AOFF + e + 1]) ++e;
        bn = blockIdx.y * 128;
        Bsel = W1b + (size_t)e * HDIM * KD;
    } else {
        int j = (blockIdx.y - 8) * 136 + blockIdx.x;
        if (j >= 256) return;
        base = (j >> 2) * 128;
        bn = (j & 3) * 128;
        Bsel = owT;
    }

    int wave = tid >> 6, lane = tid & 63;
    int lr = lane >> 3;                 // row within 8-row chunk
    int lc = ((lane & 7) ^ lr) * 8;     // swizzled col-group (elements)

    const u16* ga[4]; const u16* gb[4];
    u16* la[4]; u16* lb[4];
#pragma unroll
    for (int c = 0; c < 4; c++) {
        int tr = wave * 32 + c * 8;     // chunk base row
        if (m0) {
            int r0 = bucket_rows[base + tr + lr];
            ga[c] = ((r0 < 0) ? zeropage : xnorm + (size_t)r0 * KD) + lc;
        } else {
            ga[c] = xbf + (size_t)(base + tr + lr) * KD + lc;
        }
        gb[c] = Bsel + (size_t)(bn + tr + lr) * KD + lc;
        la[c] = &As[tr * 64];
        lb[c] = &Bs[tr * 64];
    }

    int wm = (wave & 1) * 64, wn = (wave >> 1) * 64;
    int fr = lane & 15, kq = lane >> 4, f7 = fr & 7;

    float4v acc[4][4];
#pragma unroll
    for (int i = 0; i < 4; i++)
#pragma unroll
        for (int j = 0; j < 4; j++) acc[i][j] = (float4v){0.f, 0.f, 0.f, 0.f};

    for (int k0 = 0; k0 < KD; k0 += 64) {
        __syncthreads();
#pragma unroll
        for (int c = 0; c < 4; c++) async_copy16(la[c], ga[c] + k0);
#pragma unroll
        for (int c = 0; c < 4; c++) async_copy16(lb[c], gb[c] + k0);
        __syncthreads();
        short8 af[4][2], bf[4][2];
#pragma unroll
        for (int mt = 0; mt < 4; mt++)
#pragma unroll
            for (int kh = 0; kh < 2; kh++)
                af[mt][kh] = *(const short8*)&As[(wm + mt * 16 + fr) * 64 + (((kq + 4 * kh) ^ f7) * 8)];
#pragma unroll
        for (int nt = 0; nt < 4; nt++)
#pragma unroll
            for (int kh = 0; kh < 2; kh++)
                bf[nt][kh] = *(const short8*)&Bs[(wn + nt * 16 + fr) * 64 + (((kq + 4 * kh) ^ f7) * 8)];
#pragma unroll
        for (int mt = 0; mt < 4; mt++)
#pragma unroll
            for (int nt = 0; nt < 4; nt++) {
                acc[mt][nt] = __builtin_amdgcn_mfma_f32_16x16x32_bf16(af[mt][0], bf[nt][0], acc[mt][nt], 0, 0, 0);
                acc[mt][nt] = __builtin_amdgcn_mfma_f32_16x16x32_bf16(af[mt][1], bf[nt][1], acc[mt][nt], 0, 0, 0);
            }
    }

    // epilogue: C/D layout col=lane&15, row=(lane>>4)*4+reg (m89-verified)
    int rbase = (lane >> 4) * 4, c16 = lane & 15;
#pragma unroll
    for (int nt = 0; nt < 4; nt++) {
        int gn = bn + wn + nt * 16 + c16;
        float bv = m0 ? b1[e * HDIM + gn] : 0.f;
#pragma unroll
        for (int mt = 0; mt < 4; mt++) {
            int gm = base + wm + mt * 16 + rbase;
#pragma unroll
            for (int r = 0; r < 4; r++) {
                float v = acc[mt][nt][r];
                if (m0) {
                    float h = v + bv;
                    float a = h * __builtin_amdgcn_rcpf(1.f + __expf(-h)); // fast SiLU
                    a_buf[(size_t)(gm + r) * HDIM + gn] = f2bf(a);
                } else {
                    y[(size_t)(gm + r) * ODIM + gn] = v;
                }
            }
        }
    }
}

// gemmB: a_buf @ W2[e]^T, tile 128x128, K=1024, BK=64, swizzled, fused atomic
// combine: y[row] += gate*(acc + b2[e]) (y = x@ow written by gemmA's dispatch).
__global__ __launch_bounds__(256) void gemmB_kernel(
    const u16* __restrict__ a_buf, const u16* __restrict__ W2b,
    const int* __restrict__ bucket_rows, const int* __restrict__ small,
    const float* __restrict__ b2, const float* __restrict__ gate_by_pos,
    float* __restrict__ y)
{
    constexpr int KD = 1024;
    __shared__ __align__(16) u16 As[128 * 64];
    __shared__ __align__(16) u16 Bs[128 * 64];

    int tid = threadIdx.x;
    int base = blockIdx.x * 128;
    if (base >= small[SM_AOFF + 8]) return;
    int e = 0;
    while (e < 7 && base >= small[SM_AOFF + e + 1]) ++e;
    int bn = blockIdx.y * 128;

    int wave = tid >> 6, lane = tid & 63;
    int lr = lane >> 3;
    int lc = ((lane & 7) ^ lr) * 8;

    const u16* Bsel = W2b + (size_t)e * ODIM * KD;
    const u16* ga[4]; const u16* gb[4];
    u16* la[4]; u16* lb[4];
#pragma unroll
    for (int c = 0; c < 4; c++) {
        int tr = wave * 32 + c * 8;
        ga[c] = a_buf + (size_t)(base + tr + lr) * KD + lc;
        gb[c] = Bsel + (size_t)(bn + tr + lr) * KD + lc;
        la[c] = &As[tr * 64];
        lb[c] = &Bs[tr * 64];
    }

    int wm = (wave & 1) * 64, wn = (wave >> 1) * 64;
    int fr = lane & 15, kq = lane >> 4, f7 = fr & 7;

    float4v acc[4][4];
#pragma unroll
    for (int i = 0; i < 4; i++)
#pragma unroll
        for (int j = 0; j < 4; j++) acc[i][j] = (float4v){0.f, 0.f, 0.f, 0.f};

    for (int k0 = 0; k0 < KD; k0 += 64) {
        __syncthreads();
#pragma unroll
        for (int c = 0; c < 4; c++) async_copy16(la[c], ga[c] + k0);
#pragma unroll
        for (int c = 0; c < 4; c++) async_copy16(lb[c], gb[c] + k0);
        __syncthreads();
        short8 af[4][2], bf[4][2];
#pragma unroll
        for (int mt = 0; mt < 4; mt++)
#pragma unroll
            for (int kh = 0; kh < 2; kh++)
                af[mt][kh] = *(const short8*)&As[(wm + mt * 16 + fr) * 64 + (((kq + 4 * kh) ^ f7) * 8)];
#pragma unroll
        for (int nt = 0; nt < 4; nt++)
#pragma unroll
            for (int kh = 0; kh < 2; kh++)
                bf[nt][kh] = *(const short8*)&Bs[(wn + nt * 16 + fr) * 64 + (((kq + 4 * kh) ^ f7) * 8)];
#pragma unroll
        for (int mt = 0; mt < 4; mt++)
#pragma unroll
            for (int nt = 0; nt < 4; nt++) {
                acc[mt][nt] = __builtin_amdgcn_mfma_f32_16x16x32_bf16(af[mt][0], bf[nt][0], acc[mt][nt], 0, 0, 0);
                acc[mt][nt] = __builtin_amdgcn_mfma_f32_16x16x32_bf16(af[mt][1], bf[nt][1], acc[mt][nt], 0, 0, 0);
            }
    }

    int rbase = (lane >> 4) * 4, c16 = lane & 15;
#pragma unroll
    for (int mt = 0; mt < 4; mt++) {
        int pos0 = base + wm + mt * 16 + rbase;
        int rows[4]; float gs[4];
#pragma unroll
        for (int r = 0; r < 4; r++) { rows[r] = bucket_rows[pos0 + r]; gs[r] = gate_by_pos[pos0 + r]; }
#pragma unroll
        for (int nt = 0; nt < 4; nt++) {
            int gn = bn + wn + nt * 16 + c16;
            float b2v = b2[e * ODIM + gn];
#pragma unroll
            for (int r = 0; r < 4; r++) {
                if (rows[r] >= 0)
                    unsafeAtomicAdd(&y[(size_t)rows[r] * ODIM + gn], gs[r] * (acc[mt][nt][r] + b2v));
            }
        }
    }
}

extern "C" void kernel_launch(void* const* d_in, const int* in_sizes, int n_in,
                              void* d_out, int out_size, void* d_ws, size_t ws_size,
                              hipStream_t stream)
{
    (void)in_sizes; (void)n_in; (void)out_size; (void)ws_size;
    const float* x = (const float*)d_in[0];
    // d_in[1] x_offsets, d_in[2] max_seq_len: unused by the reference math
    const float* noise = (const float*)d_in[3];
    const float* norm_w = (const float*)d_in[4];
    const float* norm_b = (const float*)d_in[5];
    const float* w_gate = (const float*)d_in[6];
    const float* w_noise = (const float*)d_in[7];
    const float* W1 = (const float*)d_in[8];
    const float* b1 = (const float*)d_in[9];
    const float* W2 = (const float*)d_in[10];
    const float* b2 = (const float*)d_in[11];
    const float* ow = (const float*)d_in[12];

    float* y = (float*)d_out;
    float* out_loss = y + (size_t)N_ROWS * ODIM;
    float* out_load = out_loss + 1;

    char* ws = (char*)d_ws;
    size_t off = 0;
    auto alloc = [&](size_t b) { size_t p = off; off = (off + b + 255) & ~(size_t)255; return p; };
    u16* xnorm_bf = (u16*)(ws + alloc((size_t)N_ROWS * DDIM * 2));
    u16* x_bf     = (u16*)(ws + alloc((size_t)N_ROWS * DDIM * 2));
    u16* W1b      = (u16*)(ws + alloc((size_t)NEXP * HDIM * DDIM * 2));
    u16* W2b      = (u16*)(ws + alloc((size_t)NEXP * ODIM * HDIM * 2));
    u16* owT      = (u16*)(ws + alloc((size_t)DDIM * ODIM * 2));
    u16* a_buf    = (u16*)(ws + alloc((size_t)MAXPOS * HDIM * 2));
    int* pair_expert = (int*)(ws + alloc((size_t)MAXPAIRS * 4));
    float* pair_gate = (float*)(ws + alloc((size_t)MAXPAIRS * 4));
    float* gate_by_pos = (float*)(ws + alloc((size_t)MAXPOS * 4));
    int* bucket_rows = (int*)(ws + alloc((size_t)MAXPOS * 4));
    int* small       = (int*)(ws + alloc(SM_WORDS * 4));
    float* zeropage  = (float*)(ws + alloc(2048));

    init1_kernel<<<1, 512, 0, stream>>>(small, zeropage);
    combo_kernel<<<GATE_BLOCKS + CONV_BLOCKS + 256 + 68, 256, 0, stream>>>(
        x, noise, norm_w, norm_b, w_gate, w_noise, W1, W2, ow,
        xnorm_bf, x_bf, pair_expert, pair_gate, W1b, W2b, owT, small, bucket_rows);
    scatter_kernel<<<MAXPAIRS / 256, 256, 0, stream>>>(pair_expert, pair_gate, small,
                                                       bucket_rows, gate_by_pos, out_loss, out_load);
    gemmA_kernel<<<dim3(MAXTILES, 10), 256, 0, stream>>>(xnorm_bf, x_bf, W1b, owT, bucket_rows,
                                                         small, b1, (const u16*)zeropage, a_buf, y);
    gemmB_kernel<<<dim3(MAXTILES, ODIM / 128), 256, 0, stream>>>(a_buf, W2b, bucket_rows, small,
                                                                 b2, gate_by_pos, y);
}

// Round 10
// 256.152 us; speedup vs baseline: 1.0911x; 1.0911x over previous
//
#include <hip/hip_runtime.h>
#include <math.h>

typedef unsigned short u16;
typedef unsigned int u32;

#define N_ROWS 8192
#define DDIM 512
#define HDIM 1024
#define ODIM 512
#define NEXP 8
#define MAXPAIRS (N_ROWS * 2)          // 16384
#define MAXPOS (MAXPAIRS + NEXP * 128) // 17408 (per-expert segments 128-aligned)
#define MAXTILES (MAXPOS / 128)        // 136

// small-region word indices (in d_ws)
#define SM_CNT 0   // 8 ints: expert lengths
#define SM_CUR 8   // 8 ints: scatter cursors
#define SM_AOFF 16 // 9 ints: aligned bucket offsets
#define SM_GSUM 32 // 8 floats: sum of gates per expert
#define SM_LSUM 40 // 8 floats: sum of load_probs per expert
#define SM_WORDS 64

using short8 = __attribute__((ext_vector_type(8))) short;
using float4v = __attribute__((ext_vector_type(4))) float;

__device__ __forceinline__ u16 f2bf(float f) {
    union { float f; u32 u; } v; v.f = f;
    u32 u = v.u;
    return (u16)((u + 0x7fffu + ((u >> 16) & 1u)) >> 16);
}

// async global->LDS, 16B per lane; HW places lane i at lds_base + i*16
__device__ __forceinline__ void async_copy16(u16* lds, const u16* g) {
    __builtin_amdgcn_global_load_lds(
        (const __attribute__((address_space(1))) void*)g,
        (__attribute__((address_space(3))) void*)lds, 16, 0, 0);
}

// ---------------- init1: zero small + zeropage ----------------
__global__ __launch_bounds__(512) void init1_kernel(int* small, float* zeropage) {
    int i = threadIdx.x;
    if (i < SM_WORDS) small[i] = 0;
    zeropage[i] = 0.f; // 512 floats
}

// ---------------- combo: gating + W1 convert + ow transpose + bucket init ----------------
// R9: W2 conversion moved into gemmA's grid (gemmA is latency-bound with idle
// VMEM; gemmB, the W2b consumer, runs after gemmA). combo = 512 gating + 4096
// W1-convert + 256 owT + 68 bucket-init blocks.
#define W1CONV_BLOCKS 4096 // (8*1024*512/4) / 256
#define GATE_BLOCKS 512    // N_ROWS/16
__global__ __launch_bounds__(256) void combo_kernel(
    const float* __restrict__ x, const float* __restrict__ noise,
    const float* __restrict__ norm_w, const float* __restrict__ norm_b,
    const float* __restrict__ w_gate, const float* __restrict__ w_noise,
    const float* __restrict__ W1, const float* __restrict__ ow,
    u16* __restrict__ xnorm_bf, u16* __restrict__ x_bf,
    int* __restrict__ pair_expert, float* __restrict__ pair_gate,
    u16* __restrict__ W1b, u16* __restrict__ owT,
    int* __restrict__ small, int* __restrict__ bucket_rows)
{
    __shared__ __align__(16) float sh[NEXP * DDIM * 2 + 64];
    int b = blockIdx.x, tid = threadIdx.x;

    if (b >= GATE_BLOCKS) {
        int cb = b - GATE_BLOCKS;
        if (cb < W1CONV_BLOCKS) {
            size_t i = (size_t)cb * 256 + tid;
            float4 v = ((const float4*)W1)[i];
            ushort4 o;
            o.x = f2bf(v.x); o.y = f2bf(v.y); o.z = f2bf(v.z); o.w = f2bf(v.w);
            ((ushort4*)W1b)[i] = o;
        } else if (cb < W1CONV_BLOCKS + 256) {
            float (*tile)[33] = (float(*)[33])sh;
            int t = cb - W1CONV_BLOCKS;
            int bx = (t & 15) * 32, by = (t >> 4) * 32;
            int tx = tid & 31, ty = tid >> 5; // 32 x 8
            for (int r = ty; r < 32; r += 8) tile[r][tx] = ow[(size_t)(by + r) * ODIM + bx + tx];
            __syncthreads();
            for (int r = ty; r < 32; r += 8) owT[(size_t)(bx + r) * DDIM + by + tx] = f2bf(tile[tx][r]);
        } else {
            int i = (cb - W1CONV_BLOCKS - 256) * 256 + tid;
            if (i < MAXPOS) bucket_rows[i] = -1;
        }
        return;
    }

    // ---- gating body (block b of 512) ----
    float* wgT = sh;                   // [e][d] transposed -> conflict-free reads
    float* wnT = sh + NEXP * DDIM;
    float* blk_g = sh + 2 * NEXP * DDIM;
    float* blk_l = blk_g + NEXP;
    int* blk_c = (int*)(blk_l + NEXP);
    float* smf = (float*)small;

    for (int i = tid; i < NEXP * DDIM; i += 256) {
        int d = i >> 3, e = i & 7;
        wgT[e * DDIM + d] = w_gate[i];
        wnT[e * DDIM + d] = w_noise[i];
    }
    if (tid < NEXP) { blk_g[tid] = 0.f; blk_l[tid] = 0.f; blk_c[tid] = 0; }
    __syncthreads();

    int wave = tid >> 6, lane = tid & 63;
    float nw[8], nb[8];
#pragma unroll
    for (int j = 0; j < 8; j++) { nw[j] = norm_w[j * 64 + lane]; nb[j] = norm_b[j * 64 + lane]; }

    for (int r = 0; r < 4; ++r) {
        int row = b * 16 + wave * 4 + r;
        const float* xr = x + (size_t)row * DDIM;
        float xv[8], s = 0.f, s2 = 0.f;
#pragma unroll
        for (int j = 0; j < 8; j++) { float v = xr[j * 64 + lane]; xv[j] = v; s += v; s2 += v * v; }
#pragma unroll
        for (int o = 32; o; o >>= 1) { s += __shfl_xor(s, o, 64); s2 += __shfl_xor(s2, o, 64); }
        float mu = s * (1.f / DDIM);
        float var = s2 * (1.f / DDIM) - mu * mu;
        float rstd = rsqrtf(var + 1e-6f);

        float acc[16];
#pragma unroll
        for (int e = 0; e < 16; e++) acc[e] = 0.f;
#pragma unroll
        for (int j = 0; j < 8; j++) {
            float v = (xv[j] - mu) * rstd * nw[j] + nb[j];
            int d = j * 64 + lane;
            xnorm_bf[(size_t)row * DDIM + d] = f2bf(v);
            x_bf[(size_t)row * DDIM + d] = f2bf(xv[j]);
#pragma unroll
            for (int e = 0; e < 8; e++) {
                acc[e] += v * wgT[e * DDIM + d];
                acc[8 + e] += v * wnT[e * DDIM + d];
            }
        }
#pragma unroll
        for (int e = 0; e < 16; e++)
#pragma unroll
            for (int o = 32; o; o >>= 1) acc[e] += __shfl_xor(acc[e], o, 64);

        float cl[8], sd[8], nz[8];
#pragma unroll
        for (int e = 0; e < 8; e++) {
            cl[e] = acc[e];
            float t = acc[8 + e];
            float sp = fmaxf(t, 0.f) + log1pf(expf(-fabsf(t))); // stable softplus
            sd[e] = sp + 0.01f;
            nz[e] = cl[e] + noise[(size_t)row * NEXP + e] * sd[e];
        }
        // top-3 (strict > = lowest-index tie-break, matching lax.top_k)
        int idx[3]; float val[3]; u32 msk = 0;
#pragma unroll
        for (int t = 0; t < 3; t++) {
            float best = -INFINITY; int bi = 0;
#pragma unroll
            for (int e = 0; e < 8; e++)
                if (!((msk >> e) & 1) && nz[e] > best) { best = nz[e]; bi = e; }
            idx[t] = bi; val[t] = best; msk |= 1u << bi;
        }
        float e1 = expf(val[1] - val[0]);
        float g0 = 1.f / (1.f + e1), g1 = e1 / (1.f + e1);
        float thr_in = val[2], thr_out = val[1];

        if (lane == 0) {
            pair_expert[row * 2] = idx[0]; pair_gate[row * 2] = g0;
            pair_expert[row * 2 + 1] = idx[1]; pair_gate[row * 2 + 1] = g1;
            atomicAdd(&blk_g[idx[0]], g0); atomicAdd(&blk_g[idx[1]], g1);
            atomicAdd(&blk_c[idx[0]], 1); atomicAdd(&blk_c[idx[1]], 1);
#pragma unroll
            for (int e = 0; e < 8; e++) {
                float thr = (nz[e] > thr_in) ? thr_in : thr_out;
                float z = (cl[e] - thr) / sd[e];
                float p = 0.5f * (1.f + erff(z * 0.70710678118654752f));
                atomicAdd(&blk_l[e], p);
            }
        }
    }
    __syncthreads();
    if (tid < NEXP) {
        atomicAdd(smf + SM_GSUM + tid, blk_g[tid]);
        atomicAdd(smf + SM_LSUM + tid, blk_l[tid]);
        atomicAdd(&small[SM_CNT + tid], blk_c[tid]);
    }
}

// ---------------- scatter (+prefix +loss +load) ----------------
__global__ __launch_bounds__(256) void scatter_kernel(
    const int* __restrict__ pair_expert, const float* __restrict__ pair_gate,
    int* __restrict__ small, int* __restrict__ bucket_rows, float* __restrict__ gate_by_pos,
    float* __restrict__ out_loss, float* __restrict__ out_load)
{
    __shared__ int aoff[NEXP + 1];
    __shared__ int blk_cnt[NEXP];
    __shared__ int blk_base[NEXP];
    int tid = threadIdx.x;
    if (tid == 0) {
        int acc = 0; aoff[0] = 0;
        for (int e = 0; e < NEXP; e++) { acc += (small[SM_CNT + e] + 127) & ~127; aoff[e + 1] = acc; }
    }
    if (tid < NEXP) blk_cnt[tid] = 0;
    __syncthreads();
    int p = blockIdx.x * 256 + tid;
    int e = pair_expert[p];
    int local = atomicAdd(&blk_cnt[e], 1);
    __syncthreads();
    if (tid < NEXP)
        blk_base[tid] = aoff[tid] + atomicAdd(&small[SM_CUR + tid], blk_cnt[tid]);
    if (blockIdx.x == 0 && tid < NEXP + 1) small[SM_AOFF + tid] = aoff[tid];
    __syncthreads();
    int pos = blk_base[e] + local;
    bucket_rows[pos] = p >> 1;
    gate_by_pos[pos] = pair_gate[p];

    if (blockIdx.x == 0 && tid == 0) {
        const float* gs = (const float*)small + SM_GSUM;
        const float* ls = (const float*)small + SM_LSUM;
        float cv[2];
        for (int t = 0; t < 2; t++) {
            const float* v = t ? ls : gs;
            float m = 0.f;
            for (int k = 0; k < NEXP; k++) m += v[k];
            m *= (1.f / NEXP);
            float var = 0.f;
            for (int k = 0; k < NEXP; k++) { float d = v[k] - m; var += d * d; }
            var *= (1.f / NEXP);
            cv[t] = var / (m * m + 1e-10f);
        }
        out_loss[0] = 0.01f * (cv[0] + cv[1]);
        int tot = 0;
        for (int k = 0; k < NEXP; k++) tot += small[SM_CNT + k];
        float inv = 1.f / (float)tot;
        for (int k = 0; k < NEXP; k++) out_load[k] = (float)small[SM_CNT + k] * inv;
    }
}

// ---------------- R9: best-of-breed gemms ----------------
// Cross-round A/B (gemmB): BK32/128x128 = ~51us (R2/R3) beats BK64/128x64=63,
// dbuf=69, splitK=76, BK64/128x128=84. gemmA best = R5 config (BK64 swizzled
// 128x128 merged, <63us). No unifying theory survived; use measured bests.

// gemmA: y<8: gathered x_norm @ W1[e]^T, +b1, SiLU -> a_buf bf16 (K=512, N=1024)
//        y=8,9: x_bf @ owT^T -> y fp32 (j=(y-8)*136+x over 64x4 tiles)
//        y>=10: W2 fp32->bf16 convert (streaming; fills gemmA's idle VMEM pipe)
__global__ __launch_bounds__(256) void gemmA_kernel(
    const u16* __restrict__ xnorm, const u16* __restrict__ xbf,
    const u16* __restrict__ W1b, const u16* __restrict__ owT,
    const float* __restrict__ W2, u16* __restrict__ W2b,
    const int* __restrict__ bucket_rows, const int* __restrict__ small,
    const float* __restrict__ b1, const u16* __restrict__ zeropage,
    u16* __restrict__ a_buf, float* __restrict__ y)
{
    constexpr int KD = 512;
    __shared__ __align__(16) u16 As[128 * 64];
    __shared__ __align__(16) u16 Bs[128 * 64];

    int tid = threadIdx.x;
    if (blockIdx.y >= 10) { // W2 convert: 2048 j-blocks x 512 float4s
        int j = (blockIdx.y - 10) * 136 + blockIdx.x;
        if (j >= 2048) return;
        size_t i = (size_t)j * 512 + tid;
#pragma unroll
        for (int t = 0; t < 2; t++, i += 256) {
            float4 v = ((const float4*)W2)[i];
            ushort4 o;
            o.x = f2bf(v.x); o.y = f2bf(v.y); o.z = f2bf(v.z); o.w = f2bf(v.w);
            ((ushort4*)W2b)[i] = o;
        }
        return;
    }

    bool m0 = blockIdx.y < 8;
    int base, bn, e = 0;
    const u16* Bsel;
    if (m0) {
        base = blockIdx.x * 128;
        if (base >= small[SM_AOFF + 8]) return;
        while (e < 7 && base >= small[SM_AOFF + e + 1]) ++e;
        bn = blockIdx.y * 128;
        Bsel = W1b + (size_t)e * HDIM * KD;
    } else {
        int j = (blockIdx.y - 8) * 136 + blockIdx.x;
        if (j >= 256) return;
        base = (j >> 2) * 128;
        bn = (j & 3) * 128;
        Bsel = owT;
    }

    int wave = tid >> 6, lane = tid & 63;
    int lr = lane >> 3;                 // row within 8-row chunk
    int lc = ((lane & 7) ^ lr) * 8;     // swizzled col-group (elements)

    const u16* ga[4]; const u16* gb[4];
    u16* la[4]; u16* lb[4];
#pragma unroll
    for (int c = 0; c < 4; c++) {
        int tr = wave * 32 + c * 8;     // chunk base row
        if (m0) {
            int r0 = bucket_rows[base + tr + lr];
            ga[c] = ((r0 < 0) ? zeropage : xnorm + (size_t)r0 * KD) + lc;
        } else {
            ga[c] = xbf + (size_t)(base + tr + lr) * KD + lc;
        }
        gb[c] = Bsel + (size_t)(bn + tr + lr) * KD + lc;
        la[c] = &As[tr * 64];
        lb[c] = &Bs[tr * 64];
    }

    int wm = (wave & 1) * 64, wn = (wave >> 1) * 64;
    int fr = lane & 15, kq = lane >> 4, f7 = fr & 7;

    float4v acc[4][4];
#pragma unroll
    for (int i = 0; i < 4; i++)
#pragma unroll
        for (int j = 0; j < 4; j++) acc[i][j] = (float4v){0.f, 0.f, 0.f, 0.f};

    for (int k0 = 0; k0 < KD; k0 += 64) {
        __syncthreads();
#pragma unroll
        for (int c = 0; c < 4; c++) async_copy16(la[c], ga[c] + k0);
#pragma unroll
        for (int c = 0; c < 4; c++) async_copy16(lb[c], gb[c] + k0);
        __syncthreads();
        short8 af[4][2], bf[4][2];
#pragma unroll
        for (int mt = 0; mt < 4; mt++)
#pragma unroll
            for (int kh = 0; kh < 2; kh++)
                af[mt][kh] = *(const short8*)&As[(wm + mt * 16 + fr) * 64 + (((kq + 4 * kh) ^ f7) * 8)];
#pragma unroll
        for (int nt = 0; nt < 4; nt++)
#pragma unroll
            for (int kh = 0; kh < 2; kh++)
                bf[nt][kh] = *(const short8*)&Bs[(wn + nt * 16 + fr) * 64 + (((kq + 4 * kh) ^ f7) * 8)];
#pragma unroll
        for (int mt = 0; mt < 4; mt++)
#pragma unroll
            for (int nt = 0; nt < 4; nt++) {
                acc[mt][nt] = __builtin_amdgcn_mfma_f32_16x16x32_bf16(af[mt][0], bf[nt][0], acc[mt][nt], 0, 0, 0);
                acc[mt][nt] = __builtin_amdgcn_mfma_f32_16x16x32_bf16(af[mt][1], bf[nt][1], acc[mt][nt], 0, 0, 0);
            }
    }

    // epilogue: C/D layout col=lane&15, row=(lane>>4)*4+reg (m89-verified)
    int rbase = (lane >> 4) * 4, c16 = lane & 15;
#pragma unroll
    for (int nt = 0; nt < 4; nt++) {
        int gn = bn + wn + nt * 16 + c16;
        float bv = m0 ? b1[e * HDIM + gn] : 0.f;
#pragma unroll
        for (int mt = 0; mt < 4; mt++) {
            int gm = base + wm + mt * 16 + rbase;
#pragma unroll
            for (int r = 0; r < 4; r++) {
                float v = acc[mt][nt][r];
                if (m0) {
                    float h = v + bv;
                    float a = h * __builtin_amdgcn_rcpf(1.f + __expf(-h)); // fast SiLU
                    a_buf[(size_t)(gm + r) * HDIM + gn] = f2bf(a);
                } else {
                    y[(size_t)(gm + r) * ODIM + gn] = v;
                }
            }
        }
    }
}

// gemmB: a_buf @ W2[e]^T, 128x128 tile, BK=32, unpadded [128][32] LDS (the
// fastest measured core, R2/R3; its ~2.1M bank conflicts are non-binding).
// Fused combine: y[row] += gate*(acc + b2[e]) via unsafeAtomicAdd.
__global__ __launch_bounds__(256) void gemmB_kernel(
    const u16* __restrict__ a_buf, const u16* __restrict__ W2b,
    const int* __restrict__ bucket_rows, const int* __restrict__ small,
    const float* __restrict__ b2, const float* __restrict__ gate_by_pos,
    float* __restrict__ y)
{
    constexpr int KD = 1024;
    __shared__ __align__(16) u16 As[128 * 32];
    __shared__ __align__(16) u16 Bs[128 * 32];

    int tid = threadIdx.x;
    int base = blockIdx.x * 128;
    if (base >= small[SM_AOFF + 8]) return;
    int e = 0;
    while (e < 7 && base >= small[SM_AOFF + e + 1]) ++e;
    int bn = blockIdx.y * 128;

    int wave = tid >> 6, lane = tid & 63;
    const int trow = wave * 32 + (lane >> 2);
    const int kcol = (lane & 3) * 8;
    const u16* ga0 = a_buf + (size_t)(base + trow) * KD + kcol;
    const u16* ga1 = a_buf + (size_t)(base + trow + 16) * KD + kcol;
    const u16* Bsel = W2b + (size_t)e * ODIM * KD;
    const u16* gb0 = Bsel + (size_t)(bn + trow) * KD + kcol;
    const u16* gb1 = Bsel + (size_t)(bn + trow + 16) * KD + kcol;
    u16* lA0 = &As[(wave * 32) * 32];
    u16* lA1 = &As[(wave * 32 + 16) * 32];
    u16* lB0 = &Bs[(wave * 32) * 32];
    u16* lB1 = &Bs[(wave * 32 + 16) * 32];

    int wm = (wave & 1) * 64, wn = (wave >> 1) * 64;
    int fr = lane & 15, kg = (lane >> 4) * 8;

    float4v acc[4][4];
#pragma unroll
    for (int i = 0; i < 4; i++)
#pragma unroll
        for (int j = 0; j < 4; j++) acc[i][j] = (float4v){0.f, 0.f, 0.f, 0.f};

    for (int k0 = 0; k0 < KD; k0 += 32) {
        __syncthreads();
        async_copy16(lA0, ga0 + k0);
        async_copy16(lA1, ga1 + k0);
        async_copy16(lB0, gb0 + k0);
        async_copy16(lB1, gb1 + k0);
        __syncthreads();
        short8 af[4], bf[4];
#pragma unroll
        for (int mt = 0; mt < 4; mt++) af[mt] = *(const short8*)&As[(wm + mt * 16 + fr) * 32 + kg];
#pragma unroll
        for (int nt = 0; nt < 4; nt++) bf[nt] = *(const short8*)&Bs[(wn + nt * 16 + fr) * 32 + kg];
#pragma unroll
        for (int mt = 0; mt < 4; mt++)
#pragma unroll
            for (int nt = 0; nt < 4; nt++)
                acc[mt][nt] = __builtin_amdgcn_mfma_f32_16x16x32_bf16(af[mt], bf[nt], acc[mt][nt], 0, 0, 0);
    }

    int rbase = (lane >> 4) * 4, c16 = lane & 15;
#pragma unroll
    for (int mt = 0; mt < 4; mt++) {
        int pos0 = base + wm + mt * 16 + rbase;
        int rows[4]; float gs[4];
#pragma unroll
        for (int r = 0; r < 4; r++) { rows[r] = bucket_rows[pos0 + r]; gs[r] = gate_by_pos[pos0 + r]; }
#pragma unroll
        for (int nt = 0; nt < 4; nt++) {
            int gn = bn + wn + nt * 16 + c16;
            float b2v = b2[e * ODIM + gn];
#pragma unroll
            for (int r = 0; r < 4; r++) {
                if (rows[r] >= 0)
                    unsafeAtomicAdd(&y[(size_t)rows[r] * ODIM + gn], gs[r] * (acc[mt][nt][r] + b2v));
            }
        }
    }
}

extern "C" void kernel_launch(void* const* d_in, const int* in_sizes, int n_in,
                              void* d_out, int out_size, void* d_ws, size_t ws_size,
                              hipStream_t stream)
{
    (void)in_sizes; (void)n_in; (void)out_size; (void)ws_size;
    const float* x = (const float*)d_in[0];
    // d_in[1] x_offsets, d_in[2] max_seq_len: unused by the reference math
    const float* noise = (const float*)d_in[3];
    const float* norm_w = (const float*)d_in[4];
    const float* norm_b = (const float*)d_in[5];
    const float* w_gate = (const float*)d_in[6];
    const float* w_noise = (const float*)d_in[7];
    const float* W1 = (const float*)d_in[8];
    const float* b1 = (const float*)d_in[9];
    const float* W2 = (const float*)d_in[10];
    const float* b2 = (const float*)d_in[11];
    const float* ow = (const float*)d_in[12];

    float* y = (float*)d_out;
    float* out_loss = y + (size_t)N_ROWS * ODIM;
    float* out_load = out_loss + 1;

    char* ws = (char*)d_ws;
    size_t off = 0;
    auto alloc = [&](size_t b) { size_t p = off; off = (off + b + 255) & ~(size_t)255; return p; };
    u16* xnorm_bf = (u16*)(ws + alloc((size_t)N_ROWS * DDIM * 2));
    u16* x_bf     = (u16*)(ws + alloc((size_t)N_ROWS * DDIM * 2));
    u16* W1b      = (u16*)(ws + alloc((size_t)NEXP * HDIM * DDIM * 2));
    u16* W2b      = (u16*)(ws + alloc((size_t)NEXP * ODIM * HDIM * 2));
    u16* owT      = (u16*)(ws + alloc((size_t)DDIM * ODIM * 2));
    u16* a_buf    = (u16*)(ws + alloc((size_t)MAXPOS * HDIM * 2));
    int* pair_expert = (int*)(ws + alloc((size_t)MAXPAIRS * 4));
    float* pair_gate = (float*)(ws + alloc((size_t)MAXPAIRS * 4));
    float* gate_by_pos = (float*)(ws + alloc((size_t)MAXPOS * 4));
    int* bucket_rows = (int*)(ws + alloc((size_t)MAXPOS * 4));
    int* small       = (int*)(ws + alloc(SM_WORDS * 4));
    float* zeropage  = (float*)(ws + alloc(2048));

    init1_kernel<<<1, 512, 0, stream>>>(small, zeropage);
    combo_kernel<<<GATE_BLOCKS + W1CONV_BLOCKS + 256 + 68, 256, 0, stream>>>(
        x, noise, norm_w, norm_b, w_gate, w_noise, W1, ow,
        xnorm_bf, x_bf, pair_expert, pair_gate, W1b, owT, small, bucket_rows);
    scatter_kernel<<<MAXPAIRS / 256, 256, 0, stream>>>(pair_expert, pair_gate, small,
                                                       bucket_rows, gate_by_pos, out_loss, out_load);
    gemmA_kernel<<<dim3(MAXTILES, 10 + 16), 256, 0, stream>>>(xnorm_bf, x_bf, W1b, owT, W2, W2b,
                                                              bucket_rows, small, b1,
                                                              (const u16*)zeropage, a_buf, y);
    gemmB_kernel<<<dim3(MAXTILES, ODIM / 128), 256, 0, stream>>>(a_buf, W2b, bucket_rows, small,
                                                                 b2, gate_by_pos, y);
}

// Round 11
// 254.896 us; speedup vs baseline: 1.0965x; 1.0049x over previous
//
#include <hip/hip_runtime.h>
#include <math.h>

typedef unsigned short u16;
typedef unsigned int u32;

#define N_ROWS 8192
#define DDIM 512
#define HDIM 1024
#define ODIM 512
#define NEXP 8
#define MAXPAIRS (N_ROWS * 2)          // 16384
#define MAXPOS (MAXPAIRS + NEXP * 128) // 17408 (per-expert segments 128-aligned)
#define MAXTILES (MAXPOS / 128)        // 136

// small-region word indices (in d_ws)
#define SM_CNT 0   // 8 ints: expert lengths
#define SM_CUR 8   // 8 ints: scatter cursors
#define SM_AOFF 16 // 9 ints: aligned bucket offsets
#define SM_GSUM 32 // 8 floats: sum of gates per expert
#define SM_LSUM 40 // 8 floats: sum of load_probs per expert
#define SM_WORDS 64

using short8 = __attribute__((ext_vector_type(8))) short;
using float4v = __attribute__((ext_vector_type(4))) float;

__device__ __forceinline__ u16 f2bf(float f) {
    union { float f; u32 u; } v; v.f = f;
    u32 u = v.u;
    return (u16)((u + 0x7fffu + ((u >> 16) & 1u)) >> 16);
}

// async global->LDS, 16B per lane; HW places lane i at lds_base + i*16
__device__ __forceinline__ void async_copy16(u16* lds, const u16* g) {
    __builtin_amdgcn_global_load_lds(
        (const __attribute__((address_space(1))) void*)g,
        (__attribute__((address_space(3))) void*)lds, 16, 0, 0);
}

// ---------------- init1: zero small + zeropage ----------------
__global__ __launch_bounds__(512) void init1_kernel(int* small, float* zeropage) {
    int i = threadIdx.x;
    if (i < SM_WORDS) small[i] = 0;
    zeropage[i] = 0.f; // 512 floats
}

// ---------------- combo: gating + W1 convert + ow transpose + bucket init + y zero ----------------
// R10: y is accumulated entirely by gemmB atomics (mode2 moved there), so
// combo also zeroes y (harness poisons it to 0xAA before every replay).
#define W1CONV_BLOCKS 4096 // (8*1024*512/4) / 256
#define GATE_BLOCKS 512    // N_ROWS/16
#define OWT_BLOCKS 256
#define BUCKET_BLOCKS 68
#define YZERO_BLOCKS 1024  // 8192*512/4 float4s / 256 threads / 4 per thread
__global__ __launch_bounds__(256) void combo_kernel(
    const float* __restrict__ x, const float* __restrict__ noise,
    const float* __restrict__ norm_w, const float* __restrict__ norm_b,
    const float* __restrict__ w_gate, const float* __restrict__ w_noise,
    const float* __restrict__ W1, const float* __restrict__ ow,
    u16* __restrict__ xnorm_bf, u16* __restrict__ x_bf,
    int* __restrict__ pair_expert, float* __restrict__ pair_gate,
    u16* __restrict__ W1b, u16* __restrict__ owT,
    int* __restrict__ small, int* __restrict__ bucket_rows, float* __restrict__ y)
{
    __shared__ __align__(16) float sh[NEXP * DDIM * 2 + 64];
    int b = blockIdx.x, tid = threadIdx.x;

    if (b >= GATE_BLOCKS) {
        int cb = b - GATE_BLOCKS;
        if (cb < W1CONV_BLOCKS) {
            size_t i = (size_t)cb * 256 + tid;
            float4 v = ((const float4*)W1)[i];
            ushort4 o;
            o.x = f2bf(v.x); o.y = f2bf(v.y); o.z = f2bf(v.z); o.w = f2bf(v.w);
            ((ushort4*)W1b)[i] = o;
        } else if (cb < W1CONV_BLOCKS + OWT_BLOCKS) {
            float (*tile)[33] = (float(*)[33])sh;
            int t = cb - W1CONV_BLOCKS;
            int bx = (t & 15) * 32, by = (t >> 4) * 32;
            int tx = tid & 31, ty = tid >> 5; // 32 x 8
            for (int r = ty; r < 32; r += 8) tile[r][tx] = ow[(size_t)(by + r) * ODIM + bx + tx];
            __syncthreads();
            for (int r = ty; r < 32; r += 8) owT[(size_t)(bx + r) * DDIM + by + tx] = f2bf(tile[tx][r]);
        } else if (cb < W1CONV_BLOCKS + OWT_BLOCKS + BUCKET_BLOCKS) {
            int i = (cb - W1CONV_BLOCKS - OWT_BLOCKS) * 256 + tid;
            if (i < MAXPOS) bucket_rows[i] = -1;
        } else {
            int zb = cb - W1CONV_BLOCKS - OWT_BLOCKS - BUCKET_BLOCKS;
            size_t i = (size_t)zb * 1024 + tid;
            float4 zero = {0.f, 0.f, 0.f, 0.f};
#pragma unroll
            for (int t = 0; t < 4; t++, i += 256) ((float4*)y)[i] = zero;
        }
        return;
    }

    // ---- gating body (block b of 512) ----
    float* wgT = sh;                   // [e][d] transposed -> conflict-free reads
    float* wnT = sh + NEXP * DDIM;
    float* blk_g = sh + 2 * NEXP * DDIM;
    float* blk_l = blk_g + NEXP;
    int* blk_c = (int*)(blk_l + NEXP);
    float* smf = (float*)small;

    for (int i = tid; i < NEXP * DDIM; i += 256) {
        int d = i >> 3, e = i & 7;
        wgT[e * DDIM + d] = w_gate[i];
        wnT[e * DDIM + d] = w_noise[i];
    }
    if (tid < NEXP) { blk_g[tid] = 0.f; blk_l[tid] = 0.f; blk_c[tid] = 0; }
    __syncthreads();

    int wave = tid >> 6, lane = tid & 63;
    float nw[8], nb[8];
#pragma unroll
    for (int j = 0; j < 8; j++) { nw[j] = norm_w[j * 64 + lane]; nb[j] = norm_b[j * 64 + lane]; }

    for (int r = 0; r < 4; ++r) {
        int row = b * 16 + wave * 4 + r;
        const float* xr = x + (size_t)row * DDIM;
        float xv[8], s = 0.f, s2 = 0.f;
#pragma unroll
        for (int j = 0; j < 8; j++) { float v = xr[j * 64 + lane]; xv[j] = v; s += v; s2 += v * v; }
#pragma unroll
        for (int o = 32; o; o >>= 1) { s += __shfl_xor(s, o, 64); s2 += __shfl_xor(s2, o, 64); }
        float mu = s * (1.f / DDIM);
        float var = s2 * (1.f / DDIM) - mu * mu;
        float rstd = rsqrtf(var + 1e-6f);

        float acc[16];
#pragma unroll
        for (int e = 0; e < 16; e++) acc[e] = 0.f;
#pragma unroll
        for (int j = 0; j < 8; j++) {
            float v = (xv[j] - mu) * rstd * nw[j] + nb[j];
            int d = j * 64 + lane;
            xnorm_bf[(size_t)row * DDIM + d] = f2bf(v);
            x_bf[(size_t)row * DDIM + d] = f2bf(xv[j]);
#pragma unroll
            for (int e = 0; e < 8; e++) {
                acc[e] += v * wgT[e * DDIM + d];
                acc[8 + e] += v * wnT[e * DDIM + d];
            }
        }
#pragma unroll
        for (int e = 0; e < 16; e++)
#pragma unroll
            for (int o = 32; o; o >>= 1) acc[e] += __shfl_xor(acc[e], o, 64);

        float cl[8], sd[8], nz[8];
#pragma unroll
        for (int e = 0; e < 8; e++) {
            cl[e] = acc[e];
            float t = acc[8 + e];
            float sp = fmaxf(t, 0.f) + log1pf(expf(-fabsf(t))); // stable softplus
            sd[e] = sp + 0.01f;
            nz[e] = cl[e] + noise[(size_t)row * NEXP + e] * sd[e];
        }
        // top-3 (strict > = lowest-index tie-break, matching lax.top_k)
        int idx[3]; float val[3]; u32 msk = 0;
#pragma unroll
        for (int t = 0; t < 3; t++) {
            float best = -INFINITY; int bi = 0;
#pragma unroll
            for (int e = 0; e < 8; e++)
                if (!((msk >> e) & 1) && nz[e] > best) { best = nz[e]; bi = e; }
            idx[t] = bi; val[t] = best; msk |= 1u << bi;
        }
        float e1 = expf(val[1] - val[0]);
        float g0 = 1.f / (1.f + e1), g1 = e1 / (1.f + e1);
        float thr_in = val[2], thr_out = val[1];

        if (lane == 0) {
            pair_expert[row * 2] = idx[0]; pair_gate[row * 2] = g0;
            pair_expert[row * 2 + 1] = idx[1]; pair_gate[row * 2 + 1] = g1;
            atomicAdd(&blk_g[idx[0]], g0); atomicAdd(&blk_g[idx[1]], g1);
            atomicAdd(&blk_c[idx[0]], 1); atomicAdd(&blk_c[idx[1]], 1);
#pragma unroll
            for (int e = 0; e < 8; e++) {
                float thr = (nz[e] > thr_in) ? thr_in : thr_out;
                float z = (cl[e] - thr) / sd[e];
                float p = 0.5f * (1.f + erff(z * 0.70710678118654752f));
                atomicAdd(&blk_l[e], p);
            }
        }
    }
    __syncthreads();
    if (tid < NEXP) {
        atomicAdd(smf + SM_GSUM + tid, blk_g[tid]);
        atomicAdd(smf + SM_LSUM + tid, blk_l[tid]);
        atomicAdd(&small[SM_CNT + tid], blk_c[tid]);
    }
}

// ---------------- scatter (+prefix +loss +load) ----------------
__global__ __launch_bounds__(256) void scatter_kernel(
    const int* __restrict__ pair_expert, const float* __restrict__ pair_gate,
    int* __restrict__ small, int* __restrict__ bucket_rows, float* __restrict__ gate_by_pos,
    float* __restrict__ out_loss, float* __restrict__ out_load)
{
    __shared__ int aoff[NEXP + 1];
    __shared__ int blk_cnt[NEXP];
    __shared__ int blk_base[NEXP];
    int tid = threadIdx.x;
    if (tid == 0) {
        int acc = 0; aoff[0] = 0;
        for (int e = 0; e < NEXP; e++) { acc += (small[SM_CNT + e] + 127) & ~127; aoff[e + 1] = acc; }
    }
    if (tid < NEXP) blk_cnt[tid] = 0;
    __syncthreads();
    int p = blockIdx.x * 256 + tid;
    int e = pair_expert[p];
    int local = atomicAdd(&blk_cnt[e], 1);
    __syncthreads();
    if (tid < NEXP)
        blk_base[tid] = aoff[tid] + atomicAdd(&small[SM_CUR + tid], blk_cnt[tid]);
    if (blockIdx.x == 0 && tid < NEXP + 1) small[SM_AOFF + tid] = aoff[tid];
    __syncthreads();
    int pos = blk_base[e] + local;
    bucket_rows[pos] = p >> 1;
    gate_by_pos[pos] = pair_gate[p];

    if (blockIdx.x == 0 && tid == 0) {
        const float* gs = (const float*)small + SM_GSUM;
        const float* ls = (const float*)small + SM_LSUM;
        float cv[2];
        for (int t = 0; t < 2; t++) {
            const float* v = t ? ls : gs;
            float m = 0.f;
            for (int k = 0; k < NEXP; k++) m += v[k];
            m *= (1.f / NEXP);
            float var = 0.f;
            for (int k = 0; k < NEXP; k++) { float d = v[k] - m; var += d * d; }
            var *= (1.f / NEXP);
            cv[t] = var / (m * m + 1e-10f);
        }
        out_loss[0] = 0.01f * (cv[0] + cv[1]);
        int tot = 0;
        for (int k = 0; k < NEXP; k++) tot += small[SM_CNT + k];
        float inv = 1.f / (float)tot;
        for (int k = 0; k < NEXP; k++) out_load[k] = (float)small[SM_CNT + k] * inv;
    }
}

// ---------------- gemmA: mode0 (R5 core: BK64 swizzled 128x128) + W2 convert ----------------
// y<8: gathered x_norm @ W1[e]^T, +b1, SiLU -> a_buf bf16 (K=512, N=1024)
// y>=8: W2 fp32->bf16 convert (streaming; fills the latency-bound gemm's idle VMEM)
__global__ __launch_bounds__(256) void gemmA_kernel(
    const u16* __restrict__ xnorm, const u16* __restrict__ W1b,
    const float* __restrict__ W2, u16* __restrict__ W2b,
    const int* __restrict__ bucket_rows, const int* __restrict__ small,
    const float* __restrict__ b1, const u16* __restrict__ zeropage,
    u16* __restrict__ a_buf)
{
    constexpr int KD = 512;
    __shared__ __align__(16) u16 As[128 * 64];
    __shared__ __align__(16) u16 Bs[128 * 64];

    int tid = threadIdx.x;
    if (blockIdx.y >= 8) { // W2 convert: 2048 j-blocks x 512 float4s
        int j = (blockIdx.y - 8) * 136 + blockIdx.x;
        if (j >= 2048) return;
        size_t i = (size_t)j * 512 + tid;
#pragma unroll
        for (int t = 0; t < 2; t++, i += 256) {
            float4 v = ((const float4*)W2)[i];
            ushort4 o;
            o.x = f2bf(v.x); o.y = f2bf(v.y); o.z = f2bf(v.z); o.w = f2bf(v.w);
            ((ushort4*)W2b)[i] = o;
        }
        return;
    }

    int base = blockIdx.x * 128;
    if (base >= small[SM_AOFF + 8]) return;
    int e = 0;
    while (e < 7 && base >= small[SM_AOFF + e + 1]) ++e;
    int bn = blockIdx.y * 128;
    const u16* Bsel = W1b + (size_t)e * HDIM * KD;

    int wave = tid >> 6, lane = tid & 63;
    int lr = lane >> 3;                 // row within 8-row chunk
    int lc = ((lane & 7) ^ lr) * 8;     // swizzled col-group (elements)

    const u16* ga[4]; const u16* gb[4];
    u16* la[4]; u16* lb[4];
#pragma unroll
    for (int c = 0; c < 4; c++) {
        int tr = wave * 32 + c * 8;     // chunk base row
        int r0 = bucket_rows[base + tr + lr];
        ga[c] = ((r0 < 0) ? zeropage : xnorm + (size_t)r0 * KD) + lc;
        gb[c] = Bsel + (size_t)(bn + tr + lr) * KD + lc;
        la[c] = &As[tr * 64];
        lb[c] = &Bs[tr * 64];
    }

    int wm = (wave & 1) * 64, wn = (wave >> 1) * 64;
    int fr = lane & 15, kq = lane >> 4, f7 = fr & 7;

    float4v acc[4][4];
#pragma unroll
    for (int i = 0; i < 4; i++)
#pragma unroll
        for (int j = 0; j < 4; j++) acc[i][j] = (float4v){0.f, 0.f, 0.f, 0.f};

    for (int k0 = 0; k0 < KD; k0 += 64) {
        __syncthreads();
#pragma unroll
        for (int c = 0; c < 4; c++) async_copy16(la[c], ga[c] + k0);
#pragma unroll
        for (int c = 0; c < 4; c++) async_copy16(lb[c], gb[c] + k0);
        __syncthreads();
        short8 af[4][2], bf[4][2];
#pragma unroll
        for (int mt = 0; mt < 4; mt++)
#pragma unroll
            for (int kh = 0; kh < 2; kh++)
                af[mt][kh] = *(const short8*)&As[(wm + mt * 16 + fr) * 64 + (((kq + 4 * kh) ^ f7) * 8)];
#pragma unroll
        for (int nt = 0; nt < 4; nt++)
#pragma unroll
            for (int kh = 0; kh < 2; kh++)
                bf[nt][kh] = *(const short8*)&Bs[(wn + nt * 16 + fr) * 64 + (((kq + 4 * kh) ^ f7) * 8)];
#pragma unroll
        for (int mt = 0; mt < 4; mt++)
#pragma unroll
            for (int nt = 0; nt < 4; nt++) {
                acc[mt][nt] = __builtin_amdgcn_mfma_f32_16x16x32_bf16(af[mt][0], bf[nt][0], acc[mt][nt], 0, 0, 0);
                acc[mt][nt] = __builtin_amdgcn_mfma_f32_16x16x32_bf16(af[mt][1], bf[nt][1], acc[mt][nt], 0, 0, 0);
            }
    }

    // epilogue: C/D layout col=lane&15, row=(lane>>4)*4+reg (m89-verified)
    int rbase = (lane >> 4) * 4, c16 = lane & 15;
#pragma unroll
    for (int nt = 0; nt < 4; nt++) {
        int gn = bn + wn + nt * 16 + c16;
        float bv = b1[e * HDIM + gn];
#pragma unroll
        for (int mt = 0; mt < 4; mt++) {
            int gm = base + wm + mt * 16 + rbase;
#pragma unroll
            for (int r = 0; r < 4; r++) {
                float h = acc[mt][nt][r] + bv;
                float a = h * __builtin_amdgcn_rcpf(1.f + __expf(-h)); // fast SiLU
                a_buf[(size_t)(gm + r) * HDIM + gn] = f2bf(a);
            }
        }
    }
}

// ---------------- gemmB: expert down-proj + mode2, all-atomic y ----------------
// R10: mode2 (x @ ow^T, independent of a_buf) migrated here to fill gemmB's
// idle CUs (544 -> 800 blocks). y pre-zeroed in combo; every contribution is
// unsafeAtomicAdd (commutative). BK32 unpadded core — fastest measured (R2/R3).
// y<4: a_buf @ W2[e]^T (K=1024), y += gate*(acc+b2[e])
// y=4,5: x_bf @ owT^T (K=512), y += acc  (j=(y-4)*136+x over 64x4 tiles)
__global__ __launch_bounds__(256) void gemmB_kernel(
    const u16* __restrict__ a_buf, const u16* __restrict__ W2b,
    const u16* __restrict__ xbf, const u16* __restrict__ owT,
    const int* __restrict__ bucket_rows, const int* __restrict__ small,
    const float* __restrict__ b2, const float* __restrict__ gate_by_pos,
    float* __restrict__ y)
{
    __shared__ __align__(16) u16 As[128 * 32];
    __shared__ __align__(16) u16 Bs[128 * 32];

    int tid = threadIdx.x;
    int wave = tid >> 6, lane = tid & 63;
    const int trow = wave * 32 + (lane >> 2);
    const int kcol = (lane & 3) * 8;
    int wm = (wave & 1) * 64, wn = (wave >> 1) * 64;
    int fr = lane & 15, kg = (lane >> 4) * 8;

    bool expertPath = blockIdx.y < 4;
    int base, bn, e = 0, KD;
    const u16 *ga0, *ga1, *gb0, *gb1;
    if (expertPath) {
        KD = 1024;
        base = blockIdx.x * 128;
        if (base >= small[SM_AOFF + 8]) return;
        while (e < 7 && base >= small[SM_AOFF + e + 1]) ++e;
        bn = blockIdx.y * 128;
        ga0 = a_buf + (size_t)(base + trow) * KD + kcol;
        ga1 = a_buf + (size_t)(base + trow + 16) * KD + kcol;
        const u16* Bsel = W2b + (size_t)e * ODIM * KD;
        gb0 = Bsel + (size_t)(bn + trow) * KD + kcol;
        gb1 = Bsel + (size_t)(bn + trow + 16) * KD + kcol;
    } else {
        KD = 512;
        int j = (blockIdx.y - 4) * 136 + blockIdx.x;
        if (j >= 256) return;
        base = (j >> 2) * 128;
        bn = (j & 3) * 128;
        ga0 = xbf + (size_t)(base + trow) * KD + kcol;
        ga1 = xbf + (size_t)(base + trow + 16) * KD + kcol;
        gb0 = owT + (size_t)(bn + trow) * KD + kcol;
        gb1 = owT + (size_t)(bn + trow + 16) * KD + kcol;
    }
    u16* lA0 = &As[(wave * 32) * 32];
    u16* lA1 = &As[(wave * 32 + 16) * 32];
    u16* lB0 = &Bs[(wave * 32) * 32];
    u16* lB1 = &Bs[(wave * 32 + 16) * 32];

    float4v acc[4][4];
#pragma unroll
    for (int i = 0; i < 4; i++)
#pragma unroll
        for (int j = 0; j < 4; j++) acc[i][j] = (float4v){0.f, 0.f, 0.f, 0.f};

    for (int k0 = 0; k0 < KD; k0 += 32) {
        __syncthreads();
        async_copy16(lA0, ga0 + k0);
        async_copy16(lA1, ga1 + k0);
        async_copy16(lB0, gb0 + k0);
        async_copy16(lB1, gb1 + k0);
        __syncthreads();
        short8 af[4], bf[4];
#pragma unroll
        for (int mt = 0; mt < 4; mt++) af[mt] = *(const short8*)&As[(wm + mt * 16 + fr) * 32 + kg];
#pragma unroll
        for (int nt = 0; nt < 4; nt++) bf[nt] = *(const short8*)&Bs[(wn + nt * 16 + fr) * 32 + kg];
#pragma unroll
        for (int mt = 0; mt < 4; mt++)
#pragma unroll
            for (int nt = 0; nt < 4; nt++)
                acc[mt][nt] = __builtin_amdgcn_mfma_f32_16x16x32_bf16(af[mt], bf[nt], acc[mt][nt], 0, 0, 0);
    }

    int rbase = (lane >> 4) * 4, c16 = lane & 15;
    if (expertPath) {
#pragma unroll
        for (int mt = 0; mt < 4; mt++) {
            int pos0 = base + wm + mt * 16 + rbase;
            int rows[4]; float gs[4];
#pragma unroll
            for (int r = 0; r < 4; r++) { rows[r] = bucket_rows[pos0 + r]; gs[r] = gate_by_pos[pos0 + r]; }
#pragma unroll
            for (int nt = 0; nt < 4; nt++) {
                int gn = bn + wn + nt * 16 + c16;
                float b2v = b2[e * ODIM + gn];
#pragma unroll
                for (int r = 0; r < 4; r++) {
                    if (rows[r] >= 0)
                        unsafeAtomicAdd(&y[(size_t)rows[r] * ODIM + gn], gs[r] * (acc[mt][nt][r] + b2v));
                }
            }
        }
    } else {
#pragma unroll
        for (int mt = 0; mt < 4; mt++) {
            int gm = base + wm + mt * 16 + rbase;
#pragma unroll
            for (int nt = 0; nt < 4; nt++) {
                int gn = bn + wn + nt * 16 + c16;
#pragma unroll
                for (int r = 0; r < 4; r++)
                    unsafeAtomicAdd(&y[(size_t)(gm + r) * ODIM + gn], acc[mt][nt][r]);
            }
        }
    }
}

extern "C" void kernel_launch(void* const* d_in, const int* in_sizes, int n_in,
                              void* d_out, int out_size, void* d_ws, size_t ws_size,
                              hipStream_t stream)
{
    (void)in_sizes; (void)n_in; (void)out_size; (void)ws_size;
    const float* x = (const float*)d_in[0];
    // d_in[1] x_offsets, d_in[2] max_seq_len: unused by the reference math
    const float* noise = (const float*)d_in[3];
    const float* norm_w = (const float*)d_in[4];
    const float* norm_b = (const float*)d_in[5];
    const float* w_gate = (const float*)d_in[6];
    const float* w_noise = (const float*)d_in[7];
    const float* W1 = (const float*)d_in[8];
    const float* b1 = (const float*)d_in[9];
    const float* W2 = (const float*)d_in[10];
    const float* b2 = (const float*)d_in[11];
    const float* ow = (const float*)d_in[12];

    float* y = (float*)d_out;
    float* out_loss = y + (size_t)N_ROWS * ODIM;
    float* out_load = out_loss + 1;

    char* ws = (char*)d_ws;
    size_t off = 0;
    auto alloc = [&](size_t b) { size_t p = off; off = (off + b + 255) & ~(size_t)255; return p; };
    u16* xnorm_bf = (u16*)(ws + alloc((size_t)N_ROWS * DDIM * 2));
    u16* x_bf     = (u16*)(ws + alloc((size_t)N_ROWS * DDIM * 2));
    u16* W1b      = (u16*)(ws + alloc((size_t)NEXP * HDIM * DDIM * 2));
    u16* W2b      = (u16*)(ws + alloc((size_t)NEXP * ODIM * HDIM * 2));
    u16* owT      = (u16*)(ws + alloc((size_t)DDIM * ODIM * 2));
    u16* a_buf    = (u16*)(ws + alloc((size_t)MAXPOS * HDIM * 2));
    int* pair_expert = (int*)(ws + alloc((size_t)MAXPAIRS * 4));
    float* pair_gate = (float*)(ws + alloc((size_t)MAXPAIRS * 4));
    float* gate_by_pos = (float*)(ws + alloc((size_t)MAXPOS * 4));
    int* bucket_rows = (int*)(ws + alloc((size_t)MAXPOS * 4));
    int* small       = (int*)(ws + alloc(SM_WORDS * 4));
    float* zeropage  = (float*)(ws + alloc(2048));

    init1_kernel<<<1, 512, 0, stream>>>(small, zeropage);
    combo_kernel<<<GATE_BLOCKS + W1CONV_BLOCKS + OWT_BLOCKS + BUCKET_BLOCKS + YZERO_BLOCKS,
                   256, 0, stream>>>(
        x, noise, norm_w, norm_b, w_gate, w_noise, W1, ow,
        xnorm_bf, x_bf, pair_expert, pair_gate, W1b, owT, small, bucket_rows, y);
    scatter_kernel<<<MAXPAIRS / 256, 256, 0, stream>>>(pair_expert, pair_gate, small,
                                                       bucket_rows, gate_by_pos, out_loss, out_load);
    gemmA_kernel<<<dim3(MAXTILES, 8 + 16), 256, 0, stream>>>(xnorm_bf, W1b, W2, W2b,
                                                             bucket_rows, small, b1,
                                                             (const u16*)zeropage, a_buf);
    gemmB_kernel<<<dim3(MAXTILES, 6), 256, 0, stream>>>(a_buf, W2b, x_bf, owT, bucket_rows,
                                                        small, b2, gate_by_pos, y);
}